// Round 1
// baseline (1200.527 us; speedup 1.0000x reference)
//
#include <hip/hip_runtime.h>
#include <math.h>

#define N_NODES 50000
#define N_EDGES 800000
#define NFEAT 512
#define NHID 256
#define NCODE 64
#define NCLASS 40

// ---------------- CSR build (by dst) ----------------
__global__ __launch_bounds__(256) void hist_kernel(const int* __restrict__ dst,
                                                   int* __restrict__ counts) {
    int t = blockIdx.x * 256 + threadIdx.x;
    if (t < N_EDGES) atomicAdd(&counts[dst[t]], 1);
}

__global__ __launch_bounds__(1024) void scan_kernel(const int* __restrict__ counts,
                                                    int* __restrict__ offsets) {
    __shared__ int sums[1024];
    int t = threadIdx.x;
    const int CH = (N_NODES + 1023) / 1024;  // 49
    int start = t * CH;
    int end = min(start + CH, N_NODES);
    int s = 0;
    for (int i = start; i < end; i++) s += counts[i];
    sums[t] = s;
    __syncthreads();
    for (int off = 1; off < 1024; off <<= 1) {
        int v = (t >= off) ? sums[t - off] : 0;
        __syncthreads();
        sums[t] += v;
        __syncthreads();
    }
    int run = (t == 0) ? 0 : sums[t - 1];
    for (int i = start; i < end; i++) {
        offsets[i] = run;
        run += counts[i];
    }
    if (t == 1023) offsets[N_NODES] = sums[1023];
}

__global__ __launch_bounds__(256) void scatter_kernel(const int* __restrict__ dst,
                                                      const int* __restrict__ offsets,
                                                      int* __restrict__ cursor,
                                                      int* __restrict__ perm) {
    int t = blockIdx.x * 256 + threadIdx.x;
    if (t < N_EDGES) {
        int d = dst[t];
        int pos = offsets[d] + atomicAdd(&cursor[d], 1);
        perm[pos] = t;
    }
}

// ---------------- GEMM1: support1 = x @ W1  [50000,512]x[512,256] ----------------
__global__ __launch_bounds__(256) void gemm1_kernel(const float* __restrict__ A,
                                                    const float* __restrict__ B,
                                                    float* __restrict__ C) {
    const int M = N_NODES, K = NFEAT, NN = NHID;
    __shared__ float As[16][132];
    __shared__ float Bs[16][132];
    int t = threadIdx.x;
    int row0 = blockIdx.x * 128, col0 = blockIdx.y * 128;
    int tx = t & 15, ty = t >> 4;
    float acc[8][8];
#pragma unroll
    for (int i = 0; i < 8; i++)
#pragma unroll
        for (int j = 0; j < 8; j++) acc[i][j] = 0.f;

    int ar = t >> 1;           // 0..127  (A tile row)
    int aks = (t & 1) * 8;     // 0 or 8  (k offset)
    int arow = row0 + ar;
    if (arow >= M) arow = M - 1;  // clamp: garbage only feeds unstored rows
    const float* Abase = A + (size_t)arow * K + aks;

    int bkr = t >> 4;          // 0..15   (B tile k-row)
    int bcs = (t & 15) * 8;    // 0..120  (B tile col)
    const float* Bbase = B + (size_t)bkr * NN + col0 + bcs;

    for (int kk = 0; kk < K; kk += 16) {
        float4 a0 = *(const float4*)(Abase + kk);
        float4 a1 = *(const float4*)(Abase + kk + 4);
        float4 b0 = *(const float4*)(Bbase + (size_t)kk * NN);
        float4 b1 = *(const float4*)(Bbase + (size_t)kk * NN + 4);
        __syncthreads();
        As[aks + 0][ar] = a0.x; As[aks + 1][ar] = a0.y;
        As[aks + 2][ar] = a0.z; As[aks + 3][ar] = a0.w;
        As[aks + 4][ar] = a1.x; As[aks + 5][ar] = a1.y;
        As[aks + 6][ar] = a1.z; As[aks + 7][ar] = a1.w;
        *(float4*)&Bs[bkr][bcs] = b0;
        *(float4*)&Bs[bkr][bcs + 4] = b1;
        __syncthreads();
#pragma unroll
        for (int k = 0; k < 16; k++) {
            float4 av0 = *(const float4*)&As[k][ty * 4];
            float4 av1 = *(const float4*)&As[k][64 + ty * 4];
            float4 bv0 = *(const float4*)&Bs[k][tx * 4];
            float4 bv1 = *(const float4*)&Bs[k][64 + tx * 4];
            float ar_[8] = {av0.x, av0.y, av0.z, av0.w, av1.x, av1.y, av1.z, av1.w};
            float bc_[8] = {bv0.x, bv0.y, bv0.z, bv0.w, bv1.x, bv1.y, bv1.z, bv1.w};
#pragma unroll
            for (int i = 0; i < 8; i++)
#pragma unroll
                for (int j = 0; j < 8; j++) acc[i][j] += ar_[i] * bc_[j];
        }
    }
#pragma unroll
    for (int i = 0; i < 8; i++) {
        int r = row0 + ((i < 4) ? (ty * 4 + i) : (64 + ty * 4 + (i - 4)));
        if (r < M) {
            float4 v0 = {acc[i][0], acc[i][1], acc[i][2], acc[i][3]};
            float4 v1 = {acc[i][4], acc[i][5], acc[i][6], acc[i][7]};
            *(float4*)(C + (size_t)r * NN + col0 + tx * 4) = v0;
            *(float4*)(C + (size_t)r * NN + col0 + 64 + tx * 4) = v1;
        }
    }
}

// ---------------- SpMM1 + bias + relu -> h1 (stored in x1cat[:,256:512]) ----------------
__global__ __launch_bounds__(256) void spmm1_kernel(const int* __restrict__ offsets,
                                                    const int* __restrict__ perm,
                                                    const int* __restrict__ src,
                                                    const float* __restrict__ w,
                                                    const float* __restrict__ support1,
                                                    const float* __restrict__ b1,
                                                    float* __restrict__ x1cat) {
    int n = blockIdx.x;
    int c = threadIdx.x;
    int beg = offsets[n], end = offsets[n + 1];
    float acc = 0.f;
    for (int i = beg; i < end; i++) {
        int e = perm[i];
        int s = src[e];
        float ww = w[e];
        acc += support1[(size_t)s * NHID + c] * ww;
    }
    float h = fmaxf(acc + b1[c], 0.f);
    x1cat[(size_t)n * (2 * NHID) + NHID + c] = h;
}

// ---------------- Fused MLP: mu/lv -> z -> x1 (stored in x1cat[:,0:256]) ----------------
__global__ __launch_bounds__(256) void mlp_kernel(const float* __restrict__ eps,
                                                  const float* __restrict__ W_mu,
                                                  const float* __restrict__ b_mu,
                                                  const float* __restrict__ W_lv,
                                                  const float* __restrict__ b_lv,
                                                  const float* __restrict__ W_dec,
                                                  const float* __restrict__ b_dec,
                                                  float* __restrict__ x1cat) {
    __shared__ float h1[8][NHID];
    __shared__ float smu[8][NCODE];
    __shared__ float slv[8][NCODE];
    __shared__ float sz[8][NCODE];
    int t = threadIdx.x;
    int node0 = blockIdx.x * 8;
#pragma unroll
    for (int n = 0; n < 8; n++)
        h1[n][t] = x1cat[(size_t)(node0 + n) * 512 + 256 + t];
    __syncthreads();
    if (t < 128) {
        int j = t & 63;
        const float* W = (t < 64) ? W_mu : W_lv;
        float bias = (t < 64) ? b_mu[j] : b_lv[j];
        float acc[8];
#pragma unroll
        for (int n = 0; n < 8; n++) acc[n] = bias;
        for (int k = 0; k < NHID; k++) {
            float wv = W[k * NCODE + j];
#pragma unroll
            for (int n = 0; n < 8; n++) acc[n] += h1[n][k] * wv;
        }
        float* dstp = (t < 64) ? &smu[0][0] : &slv[0][0];
#pragma unroll
        for (int n = 0; n < 8; n++) dstp[n * NCODE + j] = acc[n];
    }
    __syncthreads();
#pragma unroll
    for (int r = 0; r < 2; r++) {
        int idx = t + r * 256;
        int n = idx >> 6, j = idx & 63;
        sz[n][j] = smu[n][j] + eps[(size_t)(node0 + n) * NCODE + j] * expf(slv[n][j]);
    }
    __syncthreads();
    {
        float bias = b_dec[t];
        float acc[8];
#pragma unroll
        for (int n = 0; n < 8; n++) acc[n] = bias;
        for (int k = 0; k < NCODE; k++) {
            float wv = W_dec[k * NHID + t];
#pragma unroll
            for (int n = 0; n < 8; n++) acc[n] += sz[n][k] * wv;
        }
#pragma unroll
        for (int n = 0; n < 8; n++)
            x1cat[(size_t)(node0 + n) * 512 + t] = fmaxf(acc[n], 0.f);
    }
}

// ---------------- GEMM2: support2 = x1cat @ W2  [50000,512]x[512,40] ----------------
__global__ __launch_bounds__(256) void gemm2_kernel(const float* __restrict__ X,
                                                    const float* __restrict__ W2,
                                                    float* __restrict__ S2) {
    __shared__ float Ws[256 * NCLASS];  // 40 KB
    __shared__ float Xs[4][256];
    int t = threadIdx.x;
    int node0 = blockIdx.x * 32;
    int c = t & 63, n4 = t >> 6;
    float acc[8];
#pragma unroll
    for (int g = 0; g < 8; g++) acc[g] = 0.f;
    for (int kc = 0; kc < 2; kc++) {
        __syncthreads();
        for (int i = t; i < 256 * NCLASS; i += 256) Ws[i] = W2[kc * 256 * NCLASS + i];
        for (int g = 0; g < 8; g++) {
            __syncthreads();
            int nn = node0 + g * 4;
            for (int i = t; i < 1024; i += 256) {
                int ln = i >> 8;
                int kk = i & 255;
                int node = nn + ln;
                Xs[ln][kk] = (node < N_NODES) ? X[(size_t)node * 512 + kc * 256 + kk] : 0.f;
            }
            __syncthreads();
            if (c < NCLASS) {
                float a = acc[g];
                for (int k = 0; k < 256; k++) a += Xs[n4][k] * Ws[k * NCLASS + c];
                acc[g] = a;
            }
        }
    }
#pragma unroll
    for (int g = 0; g < 8; g++) {
        int node = node0 + g * 4 + n4;
        if (c < NCLASS && node < N_NODES) S2[(size_t)node * NCLASS + c] = acc[g];
    }
}

// ---------------- SpMM2 + bias + log_softmax -> out ----------------
__global__ __launch_bounds__(256) void spmm2_softmax_kernel(const int* __restrict__ offsets,
                                                            const int* __restrict__ perm,
                                                            const int* __restrict__ src,
                                                            const float* __restrict__ w,
                                                            const float* __restrict__ S2,
                                                            const float* __restrict__ b2,
                                                            float* __restrict__ out) {
    int wave = threadIdx.x >> 6;
    int lane = threadIdx.x & 63;
    int n = blockIdx.x * 4 + wave;
    int beg = offsets[n], end = offsets[n + 1];
    float acc = 0.f;
    for (int i = beg; i < end; i++) {
        int e = perm[i];
        int s = src[e];
        float ww = w[e];
        if (lane < NCLASS) acc += S2[(size_t)s * NCLASS + lane] * ww;
    }
    float v = (lane < NCLASS) ? (acc + b2[lane]) : -INFINITY;
    float m = v;
#pragma unroll
    for (int off = 32; off > 0; off >>= 1) m = fmaxf(m, __shfl_xor(m, off));
    float ex = (lane < NCLASS) ? expf(v - m) : 0.f;
    float ssum = ex;
#pragma unroll
    for (int off = 32; off > 0; off >>= 1) ssum += __shfl_xor(ssum, off);
    if (lane < NCLASS) out[(size_t)n * NCLASS + lane] = v - m - logf(ssum);
}

extern "C" void kernel_launch(void* const* d_in, const int* in_sizes, int n_in,
                              void* d_out, int out_size, void* d_ws, size_t ws_size,
                              hipStream_t stream) {
    const float* x     = (const float*)d_in[0];
    const int*   esrc  = (const int*)d_in[1];
    const int*   edst  = (const int*)d_in[2];
    const float* ew    = (const float*)d_in[3];
    const float* eps   = (const float*)d_in[4];
    const float* W1    = (const float*)d_in[5];
    const float* b1    = (const float*)d_in[6];
    const float* W_mu  = (const float*)d_in[7];
    const float* b_mu  = (const float*)d_in[8];
    const float* W_lv  = (const float*)d_in[9];
    const float* b_lv  = (const float*)d_in[10];
    const float* W_dec = (const float*)d_in[11];
    const float* b_dec = (const float*)d_in[12];
    const float* W2    = (const float*)d_in[13];
    const float* b2    = (const float*)d_in[14];
    float* out = (float*)d_out;

    // workspace layout
    float* support1 = (float*)d_ws;                                   // 12.8M f32
    float* x1cat    = support1 + (size_t)N_NODES * NHID;              // 25.6M f32
    float* support2 = x1cat + (size_t)N_NODES * 2 * NHID;             // 2M f32
    int*   counts   = (int*)(support2 + (size_t)N_NODES * NCLASS);
    int*   offsets  = counts + N_NODES;
    int*   cursor   = offsets + N_NODES + 1;
    int*   perm     = cursor + N_NODES;
    size_t need = (size_t)(perm + N_EDGES - (int*)d_ws) * sizeof(int);
    if (ws_size < need) return;  // constant across calls; fails loudly via absmax

    hipMemsetAsync(counts, 0, N_NODES * sizeof(int), stream);
    hipMemsetAsync(cursor, 0, N_NODES * sizeof(int), stream);
    hist_kernel<<<(N_EDGES + 255) / 256, 256, 0, stream>>>(edst, counts);
    scan_kernel<<<1, 1024, 0, stream>>>(counts, offsets);
    scatter_kernel<<<(N_EDGES + 255) / 256, 256, 0, stream>>>(edst, offsets, cursor, perm);

    dim3 g1((N_NODES + 127) / 128, 2);
    gemm1_kernel<<<g1, 256, 0, stream>>>(x, W1, support1);
    spmm1_kernel<<<N_NODES, 256, 0, stream>>>(offsets, perm, esrc, ew, support1, b1, x1cat);
    mlp_kernel<<<N_NODES / 8, 256, 0, stream>>>(eps, W_mu, b_mu, W_lv, b_lv, W_dec, b_dec, x1cat);
    gemm2_kernel<<<(N_NODES + 31) / 32, 256, 0, stream>>>(x1cat, W2, support2);
    spmm2_softmax_kernel<<<N_NODES / 4, 256, 0, stream>>>(offsets, perm, esrc, ew, support2, b2, out);
}

// Round 2
// 814.182 us; speedup vs baseline: 1.4745x; 1.4745x over previous
//
#include <hip/hip_runtime.h>
#include <math.h>

#define N_NODES 50000
#define N_EDGES 800000
#define NFEAT 512
#define NHID 256
#define NCODE 64
#define NCLASS 40

typedef __attribute__((ext_vector_type(8))) short short8;
typedef __attribute__((ext_vector_type(8))) unsigned short ushort8;
typedef __attribute__((ext_vector_type(4))) float floatx4;

__device__ inline unsigned short f2bf(float f) {
    unsigned u = __builtin_bit_cast(unsigned, f);
    u += 0x7fff + ((u >> 16) & 1);
    return (unsigned short)(u >> 16);
}

// ---------------- CSR build (by dst) ----------------
__global__ __launch_bounds__(256) void hist_kernel(const int* __restrict__ dst,
                                                   int* __restrict__ counts) {
    int t = blockIdx.x * 256 + threadIdx.x;
    if (t < N_EDGES) atomicAdd(&counts[dst[t]], 1);
}

__global__ __launch_bounds__(1024) void scan_kernel(const int* __restrict__ counts,
                                                    int* __restrict__ offsets) {
    __shared__ int sums[1024];
    int t = threadIdx.x;
    const int CH = (N_NODES + 1023) / 1024;  // 49
    int start = t * CH;
    int end = min(start + CH, N_NODES);
    int s = 0;
    for (int i = start; i < end; i++) s += counts[i];
    sums[t] = s;
    __syncthreads();
    for (int off = 1; off < 1024; off <<= 1) {
        int v = (t >= off) ? sums[t - off] : 0;
        __syncthreads();
        sums[t] += v;
        __syncthreads();
    }
    int run = (t == 0) ? 0 : sums[t - 1];
    for (int i = start; i < end; i++) {
        offsets[i] = run;
        run += counts[i];
    }
    if (t == 1023) offsets[N_NODES] = sums[1023];
}

// scatter edges into dst-sorted order; writes src & weight directly (no perm)
__global__ __launch_bounds__(256) void scatter_kernel(const int* __restrict__ dst,
                                                      const int* __restrict__ src,
                                                      const float* __restrict__ w,
                                                      const int* __restrict__ offsets,
                                                      int* __restrict__ cursor,
                                                      int* __restrict__ src_s,
                                                      float* __restrict__ w_s) {
    int t = blockIdx.x * 256 + threadIdx.x;
    if (t < N_EDGES) {
        int d = dst[t];
        int pos = offsets[d] + atomicAdd(&cursor[d], 1);
        src_s[pos] = src[t];
        w_s[pos] = w[t];
    }
}

// ---------------- W1 transpose+cast: W1[512][256] f32 -> W1t[256][512] bf16 ----------------
__global__ __launch_bounds__(256) void w1t_kernel(const float* __restrict__ W1,
                                                  unsigned short* __restrict__ W1t) {
    int idx = blockIdx.x * 256 + threadIdx.x;  // 512*256 = 131072
    if (idx < NFEAT * NHID) {
        int k = idx >> 8;        // 0..511
        int n = idx & 255;       // 0..255
        W1t[(size_t)n * NFEAT + k] = f2bf(W1[idx]);
    }
}

// ---------------- GEMM1 (bf16 MFMA): support1 = x @ W1  [50000,512]x[512,256] ----------------
// block: 256 threads = 4 waves; 64 rows/block; each wave: 16 rows x 256 cols
__global__ __launch_bounds__(256) void gemm1_mfma(const float* __restrict__ A,
                                                  const unsigned short* __restrict__ Bt,
                                                  float* __restrict__ C) {
    __shared__ unsigned short As[64][40];    // 64 rows x 32 k (pitch 40 for bank spread)
    __shared__ unsigned short Bs[256][40];   // 256 n x 32 k
    int t = threadIdx.x;
    int wave = t >> 6, lane = t & 63;
    int quad = lane >> 4, m16 = lane & 15;
    int m0 = blockIdx.x * 64;

    floatx4 acc[16];
#pragma unroll
    for (int i = 0; i < 16; i++) acc[i] = (floatx4){0.f, 0.f, 0.f, 0.f};

    int ar = t >> 2;            // 0..63 A row
    int ako = (t & 3) * 8;      // k offset in chunk (x8 floats)
    int arow = m0 + ar;
    if (arow >= N_NODES) arow = N_NODES - 1;
    const float* Abase = A + (size_t)arow * NFEAT + ako;
    const unsigned short* Bbase = Bt + (size_t)t * NFEAT;

    for (int k0 = 0; k0 < NFEAT; k0 += 32) {
        float4 a0 = *(const float4*)(Abase + k0);
        float4 a1 = *(const float4*)(Abase + k0 + 4);
        ushort8 b0 = *(const ushort8*)(Bbase + k0);
        ushort8 b1 = *(const ushort8*)(Bbase + k0 + 8);
        ushort8 b2 = *(const ushort8*)(Bbase + k0 + 16);
        ushort8 b3 = *(const ushort8*)(Bbase + k0 + 24);
        __syncthreads();
        ushort8 av;
        av[0] = f2bf(a0.x); av[1] = f2bf(a0.y); av[2] = f2bf(a0.z); av[3] = f2bf(a0.w);
        av[4] = f2bf(a1.x); av[5] = f2bf(a1.y); av[6] = f2bf(a1.z); av[7] = f2bf(a1.w);
        *(ushort8*)&As[ar][ako] = av;
        *(ushort8*)&Bs[t][0]  = b0;
        *(ushort8*)&Bs[t][8]  = b1;
        *(ushort8*)&Bs[t][16] = b2;
        *(ushort8*)&Bs[t][24] = b3;
        __syncthreads();
        short8 afrag = *(const short8*)&As[wave * 16 + m16][quad * 8];
#pragma unroll
        for (int nt = 0; nt < 16; nt++) {
            short8 bfrag = *(const short8*)&Bs[nt * 16 + m16][quad * 8];
            acc[nt] = __builtin_amdgcn_mfma_f32_16x16x32_bf16(afrag, bfrag, acc[nt], 0, 0, 0);
        }
    }
    // epilogue: C/D layout col=lane&15, row=quad*4+reg
#pragma unroll
    for (int nt = 0; nt < 16; nt++) {
#pragma unroll
        for (int r = 0; r < 4; r++) {
            int row = m0 + wave * 16 + quad * 4 + r;
            int col = nt * 16 + m16;
            if (row < N_NODES) C[(size_t)row * NHID + col] = acc[nt][r];
        }
    }
}

// ---------------- SpMM1 + bias + relu -> h1 (x1cat[:,256:512]) ----------------
// one wave per node, float4 per lane, 4-edge unroll
__global__ __launch_bounds__(256) void spmm1_kernel(const int* __restrict__ offsets,
                                                    const int* __restrict__ src_s,
                                                    const float* __restrict__ w_s,
                                                    const float* __restrict__ support1,
                                                    const float* __restrict__ b1,
                                                    float* __restrict__ x1cat) {
    int n = blockIdx.x * 4 + (threadIdx.x >> 6);
    int lane = threadIdx.x & 63;
    int beg = offsets[n], end = offsets[n + 1];
    float ax = 0.f, ay = 0.f, az = 0.f, aw = 0.f;
    int i = beg;
    for (; i + 4 <= end; i += 4) {
        int s0 = src_s[i], s1 = src_s[i + 1], s2 = src_s[i + 2], s3 = src_s[i + 3];
        float w0 = w_s[i], w1 = w_s[i + 1], w2 = w_s[i + 2], w3 = w_s[i + 3];
        float4 r0 = *(const float4*)&support1[(size_t)s0 * NHID + lane * 4];
        float4 r1 = *(const float4*)&support1[(size_t)s1 * NHID + lane * 4];
        float4 r2 = *(const float4*)&support1[(size_t)s2 * NHID + lane * 4];
        float4 r3 = *(const float4*)&support1[(size_t)s3 * NHID + lane * 4];
        ax += w0 * r0.x + w1 * r1.x + w2 * r2.x + w3 * r3.x;
        ay += w0 * r0.y + w1 * r1.y + w2 * r2.y + w3 * r3.y;
        az += w0 * r0.z + w1 * r1.z + w2 * r2.z + w3 * r3.z;
        aw += w0 * r0.w + w1 * r1.w + w2 * r2.w + w3 * r3.w;
    }
    for (; i < end; i++) {
        int s = src_s[i];
        float ww = w_s[i];
        float4 r = *(const float4*)&support1[(size_t)s * NHID + lane * 4];
        ax += ww * r.x; ay += ww * r.y; az += ww * r.z; aw += ww * r.w;
    }
    float4 bb = *(const float4*)&b1[lane * 4];
    float4 h;
    h.x = fmaxf(ax + bb.x, 0.f);
    h.y = fmaxf(ay + bb.y, 0.f);
    h.z = fmaxf(az + bb.z, 0.f);
    h.w = fmaxf(aw + bb.w, 0.f);
    *(float4*)&x1cat[(size_t)n * (2 * NHID) + NHID + lane * 4] = h;
}

// ---------------- Fused MLP: mu/lv -> z -> x1 (x1cat[:,0:256]), 16 nodes/block ----------------
__global__ __launch_bounds__(256) void mlp_kernel(const float* __restrict__ eps,
                                                  const float* __restrict__ W_mu,
                                                  const float* __restrict__ b_mu,
                                                  const float* __restrict__ W_lv,
                                                  const float* __restrict__ b_lv,
                                                  const float* __restrict__ W_dec,
                                                  const float* __restrict__ b_dec,
                                                  float* __restrict__ x1cat) {
    __shared__ float h1s[16][NHID];   // 16 KB
    __shared__ float smu[16][NCODE];  // 4 KB
    __shared__ float slv[16][NCODE];  // 4 KB
    __shared__ float sz[16][NCODE];   // 4 KB
    int t = threadIdx.x;
    int node0 = blockIdx.x * 16;
#pragma unroll
    for (int n = 0; n < 16; n++)
        h1s[n][t] = x1cat[(size_t)(node0 + n) * 512 + 256 + t];
    __syncthreads();
    {
        int j = t & 63;
        int which = (t >> 6) & 1;       // 0 = mu, 1 = lv
        int grp = t >> 7;               // node group: 0 -> 0..7, 1 -> 8..15
        const float* W = which ? W_lv : W_mu;
        float bias = which ? b_lv[j] : b_mu[j];
        float a[8];
#pragma unroll
        for (int n = 0; n < 8; n++) a[n] = bias;
        for (int k = 0; k < NHID; k++) {
            float wv = W[k * NCODE + j];
#pragma unroll
            for (int n = 0; n < 8; n++) a[n] = fmaf(h1s[grp * 8 + n][k], wv, a[n]);
        }
        float* dstp = which ? &slv[grp * 8][0] : &smu[grp * 8][0];
#pragma unroll
        for (int n = 0; n < 8; n++) dstp[n * NCODE + j] = a[n];
    }
    __syncthreads();
#pragma unroll
    for (int r = 0; r < 4; r++) {
        int idx = t + r * 256;
        int n = idx >> 6, j = idx & 63;
        sz[n][j] = smu[n][j] + eps[(size_t)(node0 + n) * NCODE + j] * expf(slv[n][j]);
    }
    __syncthreads();
    {
        float acc[16];
        float bias = b_dec[t];
#pragma unroll
        for (int n = 0; n < 16; n++) acc[n] = bias;
        for (int k = 0; k < NCODE; k++) {
            float wv = W_dec[k * NHID + t];
#pragma unroll
            for (int n = 0; n < 16; n++) acc[n] = fmaf(sz[n][k], wv, acc[n]);
        }
#pragma unroll
        for (int n = 0; n < 16; n++)
            x1cat[(size_t)(node0 + n) * 512 + t] = fmaxf(acc[n], 0.f);
    }
}

// ---------------- GEMM2: support2 = x1cat @ W2  [50000,512]x[512,40] ----------------
// thread = 1 node, acc[40]; X staged in LDS [k][n]; W2 rows wave-uniform (scalar loads)
__global__ __launch_bounds__(256) void gemm2_kernel(const float* __restrict__ X,
                                                    const float* __restrict__ W2,
                                                    float* __restrict__ S2) {
    __shared__ float Xs[64][257];  // 65.8 KB
    int t = threadIdx.x;
    int wave = t >> 6, lane = t & 63;
    int node0 = blockIdx.x * 256;
    int mynode = node0 + t;
    float acc[NCLASS];
#pragma unroll
    for (int c = 0; c < NCLASS; c++) acc[c] = 0.f;

    for (int k0 = 0; k0 < 512; k0 += 64) {
        __syncthreads();
        // stage 256 nodes x 64 k; wave w loads rows n = i*4 + w
        for (int i = 0; i < 64; i++) {
            int n = i * 4 + wave;
            int gn = node0 + n;
            if (gn >= N_NODES) gn = N_NODES - 1;
            Xs[lane][n] = X[(size_t)gn * 512 + k0 + lane];
        }
        __syncthreads();
        for (int kk = 0; kk < 64; kk++) {
            float xv = Xs[kk][t];
            const float* wrow = W2 + (size_t)(k0 + kk) * NCLASS;
#pragma unroll
            for (int c = 0; c < NCLASS; c++) acc[c] = fmaf(xv, wrow[c], acc[c]);
        }
    }
    if (mynode < N_NODES) {
        float* outp = S2 + (size_t)mynode * NCLASS;
#pragma unroll
        for (int c = 0; c < NCLASS; c += 4) {
            float4 v = {acc[c], acc[c + 1], acc[c + 2], acc[c + 3]};
            *(float4*)(outp + c) = v;
        }
    }
}

// ---------------- SpMM2 + bias + log_softmax -> out ----------------
__global__ __launch_bounds__(256) void spmm2_softmax_kernel(const int* __restrict__ offsets,
                                                            const int* __restrict__ src_s,
                                                            const float* __restrict__ w_s,
                                                            const float* __restrict__ S2,
                                                            const float* __restrict__ b2,
                                                            float* __restrict__ out) {
    int wave = threadIdx.x >> 6;
    int lane = threadIdx.x & 63;
    int n = blockIdx.x * 4 + wave;
    int beg = offsets[n], end = offsets[n + 1];
    float acc = 0.f;
    int i = beg;
    for (; i + 2 <= end; i += 2) {
        int s0 = src_s[i], s1 = src_s[i + 1];
        float w0 = w_s[i], w1 = w_s[i + 1];
        if (lane < NCLASS) {
            float v0 = S2[(size_t)s0 * NCLASS + lane];
            float v1 = S2[(size_t)s1 * NCLASS + lane];
            acc += w0 * v0 + w1 * v1;
        }
    }
    for (; i < end; i++) {
        int s = src_s[i];
        float ww = w_s[i];
        if (lane < NCLASS) acc += ww * S2[(size_t)s * NCLASS + lane];
    }
    float v = (lane < NCLASS) ? (acc + b2[lane]) : -INFINITY;
    float m = v;
#pragma unroll
    for (int off = 32; off > 0; off >>= 1) m = fmaxf(m, __shfl_xor(m, off));
    float ex = (lane < NCLASS) ? expf(v - m) : 0.f;
    float ssum = ex;
#pragma unroll
    for (int off = 32; off > 0; off >>= 1) ssum += __shfl_xor(ssum, off);
    if (lane < NCLASS) out[(size_t)n * NCLASS + lane] = v - m - logf(ssum);
}

extern "C" void kernel_launch(void* const* d_in, const int* in_sizes, int n_in,
                              void* d_out, int out_size, void* d_ws, size_t ws_size,
                              hipStream_t stream) {
    const float* x     = (const float*)d_in[0];
    const int*   esrc  = (const int*)d_in[1];
    const int*   edst  = (const int*)d_in[2];
    const float* ew    = (const float*)d_in[3];
    const float* eps   = (const float*)d_in[4];
    const float* W1    = (const float*)d_in[5];
    const float* b1    = (const float*)d_in[6];
    const float* W_mu  = (const float*)d_in[7];
    const float* b_mu  = (const float*)d_in[8];
    const float* W_lv  = (const float*)d_in[9];
    const float* b_lv  = (const float*)d_in[10];
    const float* W_dec = (const float*)d_in[11];
    const float* b_dec = (const float*)d_in[12];
    const float* W2    = (const float*)d_in[13];
    const float* b2    = (const float*)d_in[14];
    float* out = (float*)d_out;

    // workspace layout
    float* support1 = (float*)d_ws;                                    // 12.8M f32
    float* x1cat    = support1 + (size_t)N_NODES * NHID;               // 25.6M f32
    float* support2 = x1cat + (size_t)N_NODES * 2 * NHID;              // 2M f32
    unsigned short* W1t = (unsigned short*)(support2 + (size_t)N_NODES * NCLASS);  // 131072 u16
    int*   counts   = (int*)(W1t + (size_t)NHID * NFEAT);
    int*   offsets  = counts + N_NODES;
    int*   cursor   = offsets + N_NODES + 1;
    int*   src_s    = cursor + N_NODES;
    float* w_s      = (float*)(src_s + N_EDGES);
    size_t need = (size_t)((char*)(w_s + N_EDGES) - (char*)d_ws);
    if (ws_size < need) return;

    hipMemsetAsync(counts, 0, N_NODES * sizeof(int), stream);
    hipMemsetAsync(cursor, 0, N_NODES * sizeof(int), stream);
    hist_kernel<<<(N_EDGES + 255) / 256, 256, 0, stream>>>(edst, counts);
    scan_kernel<<<1, 1024, 0, stream>>>(counts, offsets);
    scatter_kernel<<<(N_EDGES + 255) / 256, 256, 0, stream>>>(edst, esrc, ew, offsets, cursor,
                                                              src_s, w_s);

    w1t_kernel<<<(NFEAT * NHID + 255) / 256, 256, 0, stream>>>(W1, W1t);
    gemm1_mfma<<<(N_NODES + 63) / 64, 256, 0, stream>>>(x, W1t, support1);
    spmm1_kernel<<<N_NODES / 4, 256, 0, stream>>>(offsets, src_s, w_s, support1, b1, x1cat);
    mlp_kernel<<<N_NODES / 16, 256, 0, stream>>>(eps, W_mu, b_mu, W_lv, b_lv, W_dec, b_dec, x1cat);
    gemm2_kernel<<<(N_NODES + 255) / 256, 256, 0, stream>>>(x1cat, W2, support2);
    spmm2_softmax_kernel<<<N_NODES / 4, 256, 0, stream>>>(offsets, src_s, w_s, support2, b2, out);
}